// Round 8
// baseline (1428.444 us; speedup 1.0000x reference)
//
#include <hip/hip_runtime.h>
#include <math.h>

// Problem constants (fixed by reference)
#define NB   64
#define NT   512
#define DH   1024
#define HID_OFF  33554432   // 64*512*1024
#define HC_SZ    65536      // 64*1024

// ws layout (floats):
//  [0]       A_T_ih [16][1024]
//  [16384]   A_T_hh [16][1024]
//  [32768]   M2ih   [16][256]
//  [36864]   M2hh   [16][256]
//  [106496]  pfdump [1024]       (prefetch sink, never read)
//  [107520]  y_ih   [32768][256] (32 MB)

typedef float v2f __attribute__((ext_vector_type(2)));

__device__ __forceinline__ v2f mkv2(float a, float b) { v2f r; r.x = a; r.y = b; return r; }

// Pin a value into a VGPR: the asm makes it opaque so the compiler cannot
// re-materialize the originating load inside the loop (the r4-r6 disease:
// VGPR_Count 56-64 with ~48 invariant floats re-loaded from L1/L2 per step).
#define PINF(x) asm volatile("" : "+v"(x))
#define PIN2(x) asm volatile("" : "+v"(x))

__device__ __forceinline__ void bar_lgkm() {
    // barrier that waits only for LDS/SMEM ops (NOT vmcnt) — keeps HBM
    // stores/prefetches out of the per-step critical path.
    asm volatile("s_waitcnt lgkmcnt(0)\n\ts_barrier" ::: "memory");
}

// DPP wave64 sum: result valid in lane 63. VALU-pipe only (no DS traffic).
template<int CTRL>
__device__ __forceinline__ float dpp_add(float v) {
    int m = __builtin_amdgcn_update_dpp(0, __builtin_bit_cast(int, v), CTRL, 0xf, 0xf, true);
    return v + __builtin_bit_cast(float, m);
}
__device__ __forceinline__ float wave_red_sum(float v) {
    v = dpp_add<0x111>(v);   // row_shr:1
    v = dpp_add<0x112>(v);   // row_shr:2
    v = dpp_add<0x114>(v);   // row_shr:4
    v = dpp_add<0x118>(v);   // row_shr:8  -> lane15/31/47/63 have row sums
    v = dpp_add<0x142>(v);   // row_bcast:15 -> lane31 = rows0-1, lane63 = rows2-3
    v = dpp_add<0x143>(v);   // row_bcast:31 -> lane63 = total
    return v;
}

__device__ __forceinline__ float sigm(float x) { return 1.f / (1.f + __expf(-x)); }
__device__ __forceinline__ float tanh_fast(float x) {
    float e = __expf(2.f * x);
    return 1.f - 2.f / (e + 1.f);
}

// ---------------- K0a: build A_T = (g1*g2*g3)^T and M2 = g5*g6 (both param sets)
__global__ __launch_bounds__(256) void k0_build(
    const float* __restrict__ g1a, const float* __restrict__ g2a,
    const float* __restrict__ g3a, const float* __restrict__ g5a,
    const float* __restrict__ g6a,
    const float* __restrict__ g1b, const float* __restrict__ g2b,
    const float* __restrict__ g3b, const float* __restrict__ g5b,
    const float* __restrict__ g6b,
    float* __restrict__ ATa, float* __restrict__ M2a,
    float* __restrict__ ATb, float* __restrict__ M2b)
{
    const float* g1 = blockIdx.x ? g1b : g1a;
    const float* g2 = blockIdx.x ? g2b : g2a;
    const float* g3 = blockIdx.x ? g3b : g3a;
    const float* g5 = blockIdx.x ? g5b : g5a;
    const float* g6 = blockIdx.x ? g6b : g6a;
    float* A_T = blockIdx.x ? ATb : ATa;
    float* M2  = blockIdx.x ? M2b : M2a;

    __shared__ float Lg1[128], Lg2[2048], Lg3[4096], Lg5[4096], Lg6[256], M1[1024];
    int tid = threadIdx.x;
    for (int i = tid; i < 128;  i += 256) Lg1[i] = g1[i];
    for (int i = tid; i < 2048; i += 256) Lg2[i] = g2[i];
    for (int i = tid; i < 4096; i += 256) Lg3[i] = g3[i];
    for (int i = tid; i < 4096; i += 256) Lg5[i] = g5[i];
    for (int i = tid; i < 256;  i += 256) Lg6[i] = g6[i];
    __syncthreads();
    for (int idx = tid; idx < 1024; idx += 256) {
        int i1 = idx >> 7, j = (idx >> 4) & 7, c = idx & 15;
        float s = 0.f;
        for (int a = 0; a < 16; ++a) s += Lg1[i1 * 16 + a] * Lg2[a * 128 + j * 16 + c];
        M1[idx] = s;
    }
    __syncthreads();
    // split A_T across blockIdx.y (4 slices of 4096)
    int base = 4096 * blockIdx.y;
    for (int idx = base + tid; idx < base + 4096; idx += 256) {
        int d = idx >> 10, i = idx & 1023;
        int i1 = i >> 7, j = (i >> 4) & 7, k = i & 15;
        float s = 0.f;
        for (int c = 0; c < 16; ++c) s += M1[i1 * 128 + j * 16 + c] * Lg3[c * 256 + k * 16 + d];
        A_T[idx] = s;
    }
    if (blockIdx.y == 0) {
        for (int idx = tid; idx < 4096; idx += 256) {
            int e = idx >> 8, mp = idx & 255;
            int m = mp >> 4, p = mp & 15;
            float s = 0.f;
            for (int f = 0; f < 16; ++f) s += Lg5[e * 256 + m * 16 + f] * Lg6[f * 16 + p];
            M2[idx] = s;
        }
    }
}

// ---------------- K1: y_ih[row][256] = (x[row]·A_ih)·g4ih, 2 waves per row ----
// grid 1024 x 256thr: 4 waves/block = 2 row-slots/block; 16 rows per slot.
__global__ __launch_bounds__(256) void k1_zy(
    const float* __restrict__ x, const float* __restrict__ A_T,
    const float* __restrict__ g4, float* __restrict__ y_out)
{
    __shared__ __align__(16) float Z[2][2][2][16];  // [slot][row-parity][wave-half][16]

    const int tid  = threadIdx.x;
    const int lane = tid & 63;
    const int w    = tid >> 6;          // 0..3
    const int s    = w >> 1;            // slot in block
    const int wp   = w & 1;             // i-half
    const int i0   = wp * 512 + lane * 8;

    // A slice: av[ip][dd] = {A[2dd][i0+ip], A[2dd+1][i0+ip]}  (128 VGPR, reused 16 rows)
    v2f av[8][8];
    #pragma unroll
    for (int d = 0; d < 16; ++d) {
        float Ar[8];
        *(float4*)&Ar[0] = *(const float4*)&A_T[d * 1024 + i0];
        *(float4*)&Ar[4] = *(const float4*)&A_T[d * 1024 + i0 + 4];
        #pragma unroll
        for (int ip = 0; ip < 8; ++ip) {
            if (d & 1) av[ip][d >> 1].y = Ar[ip];
            else       av[ip][d >> 1].x = Ar[ip];
        }
    }
    // g4 slice for this thread's two outputs u0, u1
    const int u0 = wp * 128 + lane;
    const int u1 = u0 + 64;
    float g4r0[16], g4r1[16];
    #pragma unroll
    for (int d = 0; d < 16; ++d) {
        g4r0[d] = g4[d * 256 + u0];
        g4r1[d] = g4[d * 256 + u1];
    }

    const int rbase = (blockIdx.x * 2 + s) * 16;
    float xr[8];
    *(float4*)&xr[0] = *(const float4*)&x[(size_t)rbase * 1024 + i0];
    *(float4*)&xr[4] = *(const float4*)&x[(size_t)rbase * 1024 + i0 + 4];

    for (int rr = 0; rr < 16; ++rr) {
        const int row = rbase + rr;
        const int rp  = rr & 1;
        // prefetch next row's x
        float xn[8];
        if (rr < 15) {
            *(float4*)&xn[0] = *(const float4*)&x[(size_t)(row + 1) * 1024 + i0];
            *(float4*)&xn[4] = *(const float4*)&x[(size_t)(row + 1) * 1024 + i0 + 4];
        }
        // partials over this lane's 8 i-values, all 16 d (v2f pairs)
        v2f p[8];
        #pragma unroll
        for (int dd = 0; dd < 8; ++dd) p[dd] = xr[0] * av[0][dd];
        #pragma unroll
        for (int ip = 1; ip < 8; ++ip)
            #pragma unroll
            for (int dd = 0; dd < 8; ++dd) p[dd] += xr[ip] * av[ip][dd];
        // DPP reduce (VALU-pipe), lane63 holds sums
        #pragma unroll
        for (int dd = 0; dd < 8; ++dd) {
            float sx = wave_red_sum(p[dd].x);
            float sy = wave_red_sum(p[dd].y);
            if (lane == 63) *(v2f*)&Z[s][rp][wp][2 * dd] = mkv2(sx, sy);
        }
        bar_lgkm();
        // gather z = half0 + half1 (broadcast b128 reads)
        float zs[16];
        {
            const float4* za = (const float4*)&Z[s][rp][0][0];
            const float4* zb = (const float4*)&Z[s][rp][1][0];
            float4 a0 = za[0], a1 = za[1], a2 = za[2], a3 = za[3];
            float4 b0 = zb[0], b1 = zb[1], b2 = zb[2], b3 = zb[3];
            *(float4*)&zs[0]  = make_float4(a0.x + b0.x, a0.y + b0.y, a0.z + b0.z, a0.w + b0.w);
            *(float4*)&zs[4]  = make_float4(a1.x + b1.x, a1.y + b1.y, a1.z + b1.z, a1.w + b1.w);
            *(float4*)&zs[8]  = make_float4(a2.x + b2.x, a2.y + b2.y, a2.z + b2.z, a2.w + b2.w);
            *(float4*)&zs[12] = make_float4(a3.x + b3.x, a3.y + b3.y, a3.z + b3.z, a3.w + b3.w);
        }
        float y0 = zs[0] * g4r0[0], y1 = zs[0] * g4r1[0];
        #pragma unroll
        for (int d = 1; d < 16; ++d) {
            y0 = fmaf(zs[d], g4r0[d], y0);
            y1 = fmaf(zs[d], g4r1[d], y1);
        }
        y_out[(size_t)row * 256 + u0] = y0;
        y_out[(size_t)row * 256 + u1] = y1;
        #pragma unroll
        for (int ip = 0; ip < 8; ++ip) xr[ip] = xn[ip];
        // no 2nd barrier: next write goes to row-parity ^1 buffer; the write
        // after that is separated from this read by the next bar_lgkm.
    }
}

// ---------------- K2: sequential LSTM, one block (CU) per batch row ----------
// Two barriers/step. Rank-factored hh path with the W tensor computed
// WAVE-LOCALLY (each wave computes the 4 w-rows it consumes, 4x redundant,
// ordered by an in-wave lgkmcnt(0) — no 3rd barrier). All loop-invariant
// weight slices are asm-pinned into VGPRs (r6 counter showed VGPR=56: the
// allocator was re-loading ~48 invariant floats/thread/step from L1/L2).
// Prefetch retire is 4-deep rotated so its vmcnt wait is auto-satisfied.
__global__ __launch_bounds__(1024)
__attribute__((amdgpu_waves_per_eu(4, 4)))
void k2_lstm(
    const float* __restrict__ A_T_hh, const float* __restrict__ g4hh,
    const float* __restrict__ M2hh,
    const float* __restrict__ M2ih, const float* __restrict__ y_ih_g,
    const float* __restrict__ b_ih, const float* __restrict__ b_hh,
    float* __restrict__ pfdump, float* __restrict__ out)
{
    __shared__ __align__(16) float Lh[1024];
    __shared__ __align__(16) float Lz[2][16];   // [wsl][d] z partials (no parity needed:
                                                // reads drain at bar#2 before next write)
    __shared__ __align__(16) float Lw[16][64];  // per-wave private w rows [g*16+e]

    const int tid  = threadIdx.x;
    const int b    = blockIdx.x;
    const int lane = tid & 63;
    const int w    = tid >> 6;               // wave 0..15
    const int dg   = w >> 1;                 // d-pair group 0..7 -> d = 2dg, 2dg+1
    const int wsl  = w & 1;                  // i-half
    const int mp   = tid & 255;
    const int n0   = tid >> 8;               // 0..3, wave-uniform

    // z-phase A slice: 2 d-rows x 8 i per lane, stride-2 v2f (2-way LDS aliasing = free)
    const int ibase = wsl * 512 + 2 * lane;
    v2f a0p[4], a1p[4];
    #pragma unroll
    for (int k = 0; k < 4; ++k) {
        a0p[k] = *(const v2f*)&A_T_hh[(2 * dg) * 1024 + ibase + 128 * k];
        a1p[k] = *(const v2f*)&A_T_hh[(2 * dg + 1) * 1024 + ibase + 128 * k];
        PIN2(a0p[k]); PIN2(a1p[k]);
    }

    // W slice: lane computes w[nl][el], nl = 4*(lane>>4)+n0 (exactly the rows
    // this wave's D1 consumes), el = lane&15.
    const int nl = 4 * (lane >> 4) + n0;
    const int el = lane & 15;
    float g4w[16];
    #pragma unroll
    for (int d = 0; d < 16; ++d) { g4w[d] = g4hh[d * 256 + nl * 16 + el]; PINF(g4w[d]); }

    // D1 weights: m2v[k] = {M2hh[2k][mp], M2hh[2k+1][mp]}
    v2f m2v[8];
    #pragma unroll
    for (int k = 0; k < 8; ++k) {
        m2v[k] = mkv2(M2hh[(2 * k) * 256 + mp], M2hh[(2 * k + 1) * 256 + mp]);
        PIN2(m2v[k]);
    }

    // D2 weights (ih): m2i[e] = M2ih[e][mp]
    float m2i[16];
    #pragma unroll
    for (int e = 0; e < 16; ++e) { m2i[e] = M2ih[e * 256 + mp]; PINF(m2i[e]); }

    float bias0 = b_ih[tid]        + b_hh[tid];
    float bias1 = b_ih[1024 + tid] + b_hh[1024 + tid];
    float bias2 = b_ih[2048 + tid] + b_hh[2048 + tid];
    float bias3 = b_ih[3072 + tid] + b_hh[3072 + tid];
    PINF(bias0); PINF(bias1); PINF(bias2); PINF(bias3);

    Lh[tid] = 0.f;
    float h = 0.f, c = 0.f;
    float yp0 = 0.f, yp1 = 0.f, yp2 = 0.f, yp3 = 0.f;  // rotating prefetch retire
    __syncthreads();

    const float* yrow = y_ih_g + (size_t)b * (NT * 256);
    float*       orow = out + (size_t)b * (NT * 1024);
    float pfacc = 0.f;

    for (int t = 0; t < NT; ++t) {
        // (0) scalar y loads for THIS step (wave-uniform -> s_load, lands in
        //     phase A) + L2-warming vector load 4 steps ahead (vmcnt-only,
        //     retired via the 4-deep rotation — never stalls this step).
        const int ybase = __builtin_amdgcn_readfirstlane(t * 256 + n0 * 16);
        float yv[4][16];
        #pragma unroll
        for (int g = 0; g < 4; ++g)
            #pragma unroll
            for (int e = 0; e < 16; ++e)
                yv[g][e] = yrow[ybase + g * 64 + e];
        float ypn = 0.f;
        {
            int tpf = (t + 4 < NT) ? (t + 4) : (NT - 1);
            if (tid < 256) ypn = yrow[tpf * 256 + tid];
        }

        // --- (A) z partials: wave (dg,wsl) covers d={2dg,2dg+1}, i in [wsl*512,+512)
        float p0, p1;
        {
            const v2f* hv2 = (const v2f*)&Lh[ibase];
            v2f hp0 = hv2[0], hp1 = hv2[64], hp2 = hv2[128], hp3 = hv2[192];
            v2f s0 = hp0 * a0p[0]; s0 += hp1 * a0p[1]; s0 += hp2 * a0p[2]; s0 += hp3 * a0p[3];
            v2f s1 = hp0 * a1p[0]; s1 += hp1 * a1p[1]; s1 += hp2 * a1p[2]; s1 += hp3 * a1p[3];
            p0 = s0.x + s0.y;
            p1 = s1.x + s1.y;
        }
        p0 = wave_red_sum(p0);              // DPP, VALU pipe
        p1 = wave_red_sum(p1);
        if (lane == 63) *(v2f*)&Lz[wsl][2 * dg] = mkv2(p0, p1);  // plain write

        // --- (D2, hoisted) bias + ih contribution — independent of z, fills the
        //     DPP latency window and shortens the post-barrier chain.
        float acc0 = bias0, acc1 = bias1, acc2 = bias2, acc3 = bias3;
        #pragma unroll
        for (int e = 0; e < 16; ++e) {
            acc0 = fmaf(yv[0][e], m2i[e], acc0);
            acc1 = fmaf(yv[1][e], m2i[e], acc1);
            acc2 = fmaf(yv[2][e], m2i[e], acc2);
            acc3 = fmaf(yv[3][e], m2i[e], acc3);
        }
        bar_lgkm();   // bar#1: z partials visible

        // --- (W, wave-local) lane computes w[nl][el]; ordered by in-wave lgkm
        {
            float zs[16];
            const float4* za = (const float4*)&Lz[0][0];
            const float4* zb = (const float4*)&Lz[1][0];
            float4 a0 = za[0], a1 = za[1], a2 = za[2], a3 = za[3];
            float4 b0 = zb[0], b1 = zb[1], b2 = zb[2], b3 = zb[3];
            *(float4*)&zs[0]  = make_float4(a0.x + b0.x, a0.y + b0.y, a0.z + b0.z, a0.w + b0.w);
            *(float4*)&zs[4]  = make_float4(a1.x + b1.x, a1.y + b1.y, a1.z + b1.z, a1.w + b1.w);
            *(float4*)&zs[8]  = make_float4(a2.x + b2.x, a2.y + b2.y, a2.z + b2.z, a2.w + b2.w);
            *(float4*)&zs[12] = make_float4(a3.x + b3.x, a3.y + b3.y, a3.z + b3.z, a3.w + b3.w);
            float wa = zs[0] * g4w[0], wb = zs[1] * g4w[1];
            #pragma unroll
            for (int d = 2; d < 16; d += 2) {
                wa = fmaf(zs[d],     g4w[d],     wa);
                wb = fmaf(zs[d + 1], g4w[d + 1], wb);
            }
            Lw[w][lane] = wa + wb;
        }
        // in-wave RAW ordering: drain the ds_write (and zs reads) before the
        // wave-private broadcast reads below. No s_barrier — same wave only.
        asm volatile("s_waitcnt lgkmcnt(0)" ::: "memory");

        // --- (D1) hh contribution from this wave's own w rows (broadcast b128)
        #pragma unroll
        for (int g = 0; g < 4; ++g) {
            const float4* wr4 = (const float4*)&Lw[w][g * 16];
            float4 f0 = wr4[0], f1 = wr4[1], f2 = wr4[2], f3 = wr4[3];
            v2f A = mkv2(f0.x, f0.y) * m2v[0];
            A += mkv2(f0.z, f0.w) * m2v[1];
            A += mkv2(f1.x, f1.y) * m2v[2];
            A += mkv2(f1.z, f1.w) * m2v[3];
            A += mkv2(f2.x, f2.y) * m2v[4];
            A += mkv2(f2.z, f2.w) * m2v[5];
            A += mkv2(f3.x, f3.y) * m2v[6];
            A += mkv2(f3.z, f3.w) * m2v[7];
            float d1 = A.x + A.y;
            if (g == 0) acc0 += d1;
            else if (g == 1) acc1 += d1;
            else if (g == 2) acc2 += d1;
            else acc3 += d1;
        }

        // --- (E) LSTM cell
        float ig = sigm(acc0);
        float fg = sigm(acc1);
        float gg = tanh_fast(acc2);
        float og = sigm(acc3);
        c = fg * c + ig * gg;
        h = og * tanh_fast(c);

        Lh[tid] = h;
        orow[t * 1024 + tid] = h;           // fire-and-forget (vmcnt, not drained by bar)
        // retire the prefetch issued 3 steps ago: vmcnt wait is auto-satisfied
        // (6+ newer vmem ops outstanding), so no stall — unlike r4-r6's
        // same-step retire which exposed ~HBM latency + the store ack.
        pfacc += yp0; yp0 = yp1; yp1 = yp2; yp2 = yp3; yp3 = ypn;
        bar_lgkm();   // bar#2: Lh(t) + Lz/Lw reads drained; next step may overwrite
    }

    out[HID_OFF + b * 1024 + tid] = h;
    out[HID_OFF + HC_SZ + b * 1024 + tid] = c;
    float pfsink = pfacc + yp0 + yp1 + yp2 + yp3;
    if (tid < 256) pfdump[tid] = pfsink;     // sink (ws, never read)
}

extern "C" void kernel_launch(void* const* d_in, const int* in_sizes, int n_in,
                              void* d_out, int out_size, void* d_ws, size_t ws_size,
                              hipStream_t stream) {
    const float* x     = (const float*)d_in[0];
    const float* ihg1  = (const float*)d_in[1];
    const float* ihg2  = (const float*)d_in[2];
    const float* ihg3  = (const float*)d_in[3];
    const float* ihg4  = (const float*)d_in[4];
    const float* ihg5  = (const float*)d_in[5];
    const float* ihg6  = (const float*)d_in[6];
    const float* hhg1  = (const float*)d_in[7];
    const float* hhg2  = (const float*)d_in[8];
    const float* hhg3  = (const float*)d_in[9];
    const float* hhg4  = (const float*)d_in[10];
    const float* hhg5  = (const float*)d_in[11];
    const float* hhg6  = (const float*)d_in[12];
    const float* b_ih  = (const float*)d_in[13];
    const float* b_hh  = (const float*)d_in[14];
    float* out = (float*)d_out;

    float* ws     = (float*)d_ws;
    float* ATih   = ws;
    float* AThh   = ws + 16384;
    float* M2ih   = ws + 32768;
    float* M2hh   = ws + 36864;
    float* pfdump = ws + 106496;
    float* yih    = ws + 107520;

    hipLaunchKernelGGL(k0_build, dim3(2, 4), dim3(256), 0, stream,
                       ihg1, ihg2, ihg3, ihg5, ihg6,
                       hhg1, hhg2, hhg3, hhg5, hhg6,
                       ATih, M2ih, AThh, M2hh);
    hipLaunchKernelGGL(k1_zy, dim3(1024), dim3(256), 0, stream,
                       x, ATih, ihg4, yih);
    hipLaunchKernelGGL(k2_lstm, dim3(NB), dim3(1024), 0, stream,
                       AThh, hhg4, M2hh, M2ih, yih, b_ih, b_hh, pfdump, out);
}

// Round 9
// 1408.405 us; speedup vs baseline: 1.0142x; 1.0142x over previous
//
#include <hip/hip_runtime.h>
#include <math.h>

// Problem constants (fixed by reference)
#define NB   64
#define NT   512
#define DH   1024
#define HID_OFF  33554432   // 64*512*1024
#define HC_SZ    65536      // 64*1024

// ws layout (floats):
//  [0]       A_T_ih [16][1024]
//  [16384]   A_T_hh [16][1024]
//  [32768]   M2ih   [16][256]
//  [36864]   M2hh   [16][256]
//  [40960]   Whh2   [4096][16]   (g4hh x M2hh folded, u-major)
//  [106496]  pfdump [1024]       (prefetch sink, never read)
//  [107520]  y_ih   [32768][256] (32 MB)

typedef float v2f __attribute__((ext_vector_type(2)));

__device__ __forceinline__ v2f mkv2(float a, float b) { v2f r; r.x = a; r.y = b; return r; }

__device__ __forceinline__ void bar_lgkm() {
    // barrier that waits only for LDS/SMEM ops (NOT vmcnt) — keeps HBM
    // stores/prefetches out of the per-step critical path.
    asm volatile("s_waitcnt lgkmcnt(0)\n\ts_barrier" ::: "memory");
}

// DPP wave64 sum: result valid in lane 63. VALU-pipe only (no DS traffic).
template<int CTRL>
__device__ __forceinline__ float dpp_add(float v) {
    int m = __builtin_amdgcn_update_dpp(0, __builtin_bit_cast(int, v), CTRL, 0xf, 0xf, true);
    return v + __builtin_bit_cast(float, m);
}
__device__ __forceinline__ float wave_red_sum(float v) {
    v = dpp_add<0x111>(v);   // row_shr:1
    v = dpp_add<0x112>(v);   // row_shr:2
    v = dpp_add<0x114>(v);   // row_shr:4
    v = dpp_add<0x118>(v);   // row_shr:8  -> lane15/31/47/63 have row sums
    v = dpp_add<0x142>(v);   // row_bcast:15 -> lane31 = rows0-1, lane63 = rows2-3
    v = dpp_add<0x143>(v);   // row_bcast:31 -> lane63 = total
    return v;
}

__device__ __forceinline__ float sigm(float x) { return 1.f / (1.f + __expf(-x)); }
__device__ __forceinline__ float tanh_fast(float x) {
    float e = __expf(2.f * x);
    return 1.f - 2.f / (e + 1.f);
}

// ---------------- K0a: build A_T = (g1*g2*g3)^T and M2 = g5*g6 (both param sets)
__global__ __launch_bounds__(256) void k0_build(
    const float* __restrict__ g1a, const float* __restrict__ g2a,
    const float* __restrict__ g3a, const float* __restrict__ g5a,
    const float* __restrict__ g6a,
    const float* __restrict__ g1b, const float* __restrict__ g2b,
    const float* __restrict__ g3b, const float* __restrict__ g5b,
    const float* __restrict__ g6b,
    float* __restrict__ ATa, float* __restrict__ M2a,
    float* __restrict__ ATb, float* __restrict__ M2b)
{
    const float* g1 = blockIdx.x ? g1b : g1a;
    const float* g2 = blockIdx.x ? g2b : g2a;
    const float* g3 = blockIdx.x ? g3b : g3a;
    const float* g5 = blockIdx.x ? g5b : g5a;
    const float* g6 = blockIdx.x ? g6b : g6a;
    float* A_T = blockIdx.x ? ATb : ATa;
    float* M2  = blockIdx.x ? M2b : M2a;

    __shared__ float Lg1[128], Lg2[2048], Lg3[4096], Lg5[4096], Lg6[256], M1[1024];
    int tid = threadIdx.x;
    for (int i = tid; i < 128;  i += 256) Lg1[i] = g1[i];
    for (int i = tid; i < 2048; i += 256) Lg2[i] = g2[i];
    for (int i = tid; i < 4096; i += 256) Lg3[i] = g3[i];
    for (int i = tid; i < 4096; i += 256) Lg5[i] = g5[i];
    for (int i = tid; i < 256;  i += 256) Lg6[i] = g6[i];
    __syncthreads();
    for (int idx = tid; idx < 1024; idx += 256) {
        int i1 = idx >> 7, j = (idx >> 4) & 7, c = idx & 15;
        float s = 0.f;
        for (int a = 0; a < 16; ++a) s += Lg1[i1 * 16 + a] * Lg2[a * 128 + j * 16 + c];
        M1[idx] = s;
    }
    __syncthreads();
    // split A_T across blockIdx.y (4 slices of 4096)
    int base = 4096 * blockIdx.y;
    for (int idx = base + tid; idx < base + 4096; idx += 256) {
        int d = idx >> 10, i = idx & 1023;
        int i1 = i >> 7, j = (i >> 4) & 7, k = i & 15;
        float s = 0.f;
        for (int c = 0; c < 16; ++c) s += M1[i1 * 128 + j * 16 + c] * Lg3[c * 256 + k * 16 + d];
        A_T[idx] = s;
    }
    if (blockIdx.y == 0) {
        for (int idx = tid; idx < 4096; idx += 256) {
            int e = idx >> 8, mp = idx & 255;
            int m = mp >> 4, p = mp & 15;
            float s = 0.f;
            for (int f = 0; f < 16; ++f) s += Lg5[e * 256 + m * 16 + f] * Lg6[f * 16 + p];
            M2[idx] = s;
        }
    }
}

// ---------------- K0b: Whh2[u][d] = sum_e g4hh[d, n(u), e] * M2hh[e, mp(u)] ----
__global__ __launch_bounds__(256) void k0b_whh(
    const float* __restrict__ g4hh, const float* __restrict__ M2hh,
    float* __restrict__ Whh2)
{
    int n = blockIdx.x;         // 0..15
    int mp = threadIdx.x;       // 0..255
    __shared__ float Ls[256];   // [d][e] slice for this n
    Ls[mp] = g4hh[(mp >> 4) * 256 + n * 16 + (mp & 15)];
    float m2loc[16];
    #pragma unroll
    for (int e = 0; e < 16; ++e) m2loc[e] = M2hh[e * 256 + mp];
    __syncthreads();
    float wv[16];
    #pragma unroll
    for (int d = 0; d < 16; ++d) {
        float s = 0.f;
        #pragma unroll
        for (int e = 0; e < 16; ++e) s = fmaf(Ls[d * 16 + e], m2loc[e], s);
        wv[d] = s;
    }
    float4* dst = (float4*)&Whh2[(size_t)(n * 256 + mp) * 16];
    dst[0] = make_float4(wv[0], wv[1], wv[2], wv[3]);
    dst[1] = make_float4(wv[4], wv[5], wv[6], wv[7]);
    dst[2] = make_float4(wv[8], wv[9], wv[10], wv[11]);
    dst[3] = make_float4(wv[12], wv[13], wv[14], wv[15]);
}

// ---------------- K1: y_ih[row][256] = (x[row]·A_ih)·g4ih, 2 waves per row ----
// grid 1024 x 256thr: 4 waves/block = 2 row-slots/block; 16 rows per slot.
__global__ __launch_bounds__(256) void k1_zy(
    const float* __restrict__ x, const float* __restrict__ A_T,
    const float* __restrict__ g4, float* __restrict__ y_out)
{
    __shared__ __align__(16) float Z[2][2][2][16];  // [slot][row-parity][wave-half][16]

    const int tid  = threadIdx.x;
    const int lane = tid & 63;
    const int w    = tid >> 6;          // 0..3
    const int s    = w >> 1;            // slot in block
    const int wp   = w & 1;             // i-half
    const int i0   = wp * 512 + lane * 8;

    // A slice: av[ip][dd] = {A[2dd][i0+ip], A[2dd+1][i0+ip]}  (128 VGPR, reused 16 rows)
    v2f av[8][8];
    #pragma unroll
    for (int d = 0; d < 16; ++d) {
        float Ar[8];
        *(float4*)&Ar[0] = *(const float4*)&A_T[d * 1024 + i0];
        *(float4*)&Ar[4] = *(const float4*)&A_T[d * 1024 + i0 + 4];
        #pragma unroll
        for (int ip = 0; ip < 8; ++ip) {
            if (d & 1) av[ip][d >> 1].y = Ar[ip];
            else       av[ip][d >> 1].x = Ar[ip];
        }
    }
    // g4 slice for this thread's two outputs u0, u1
    const int u0 = wp * 128 + lane;
    const int u1 = u0 + 64;
    float g4r0[16], g4r1[16];
    #pragma unroll
    for (int d = 0; d < 16; ++d) {
        g4r0[d] = g4[d * 256 + u0];
        g4r1[d] = g4[d * 256 + u1];
    }

    const int rbase = (blockIdx.x * 2 + s) * 16;
    float xr[8];
    *(float4*)&xr[0] = *(const float4*)&x[(size_t)rbase * 1024 + i0];
    *(float4*)&xr[4] = *(const float4*)&x[(size_t)rbase * 1024 + i0 + 4];

    for (int rr = 0; rr < 16; ++rr) {
        const int row = rbase + rr;
        const int rp  = rr & 1;
        // prefetch next row's x
        float xn[8];
        if (rr < 15) {
            *(float4*)&xn[0] = *(const float4*)&x[(size_t)(row + 1) * 1024 + i0];
            *(float4*)&xn[4] = *(const float4*)&x[(size_t)(row + 1) * 1024 + i0 + 4];
        }
        // partials over this lane's 8 i-values, all 16 d (v2f pairs)
        v2f p[8];
        #pragma unroll
        for (int dd = 0; dd < 8; ++dd) p[dd] = xr[0] * av[0][dd];
        #pragma unroll
        for (int ip = 1; ip < 8; ++ip)
            #pragma unroll
            for (int dd = 0; dd < 8; ++dd) p[dd] += xr[ip] * av[ip][dd];
        // DPP reduce (VALU-pipe), lane63 holds sums
        #pragma unroll
        for (int dd = 0; dd < 8; ++dd) {
            float sx = wave_red_sum(p[dd].x);
            float sy = wave_red_sum(p[dd].y);
            if (lane == 63) *(v2f*)&Z[s][rp][wp][2 * dd] = mkv2(sx, sy);
        }
        bar_lgkm();
        // gather z = half0 + half1 (broadcast b128 reads)
        float zs[16];
        {
            const float4* za = (const float4*)&Z[s][rp][0][0];
            const float4* zb = (const float4*)&Z[s][rp][1][0];
            float4 a0 = za[0], a1 = za[1], a2 = za[2], a3 = za[3];
            float4 b0 = zb[0], b1 = zb[1], b2 = zb[2], b3 = zb[3];
            *(float4*)&zs[0]  = make_float4(a0.x + b0.x, a0.y + b0.y, a0.z + b0.z, a0.w + b0.w);
            *(float4*)&zs[4]  = make_float4(a1.x + b1.x, a1.y + b1.y, a1.z + b1.z, a1.w + b1.w);
            *(float4*)&zs[8]  = make_float4(a2.x + b2.x, a2.y + b2.y, a2.z + b2.z, a2.w + b2.w);
            *(float4*)&zs[12] = make_float4(a3.x + b3.x, a3.y + b3.y, a3.z + b3.z, a3.w + b3.w);
        }
        float y0 = zs[0] * g4r0[0], y1 = zs[0] * g4r1[0];
        #pragma unroll
        for (int d = 1; d < 16; ++d) {
            y0 = fmaf(zs[d], g4r0[d], y0);
            y1 = fmaf(zs[d], g4r1[d], y1);
        }
        y_out[(size_t)row * 256 + u0] = y0;
        y_out[(size_t)row * 256 + u1] = y1;
        #pragma unroll
        for (int ip = 0; ip < 8; ++ip) xr[ip] = xn[ip];
        // no 2nd barrier: next write goes to row-parity ^1 buffer; the write
        // after that is separated from this read by the next bar_lgkm.
    }
}

// ---------------- K2: sequential LSTM, one block (CU) per batch row ----------
// r8 was LDS-BANDWIDTH-bound: ~450 KB/step/CU of per-lane LDS reads (Lh 64K +
// z broadcast-gather 128K + Lw 256K) ≈ 5300 cy at 85 B/cy — the whole step.
// r9: (1) z goes to SGPRs via an 8-byte/lane ds_read2 + 16 v_readlane —
// LDS 128K→8K; (2) D1 uses the folded Whh2 table as a per-thread 64-float
// REGISTER array with SGPR-z fmacs — LDS 256K→0; (3) register residency is
// forced by ALIASING, not pins: weight pointers and `out` are NOT restrict,
// so the per-step orow store makes in-loop remat of the pre-loop weight
// loads illegal. y_ih_g keeps restrict so yv stays on the s_load/SGPR path.
__global__ __launch_bounds__(1024)
__attribute__((amdgpu_waves_per_eu(4, 4)))
void k2_lstm(
    const float* A_T_hh, const float* Whh2, const float* M2ih,
    const float* __restrict__ y_ih_g,
    const float* b_ih, const float* b_hh,
    float* __restrict__ pfdump, float* out)
{
    __shared__ __align__(16) float Lh[1024];
    __shared__ __align__(16) float Lz[2][16];   // [wsl][d] z partials

    const int tid  = threadIdx.x;
    const int b    = blockIdx.x;
    const int lane = tid & 63;
    const int w    = tid >> 6;               // wave 0..15
    const int dg   = w >> 1;                 // d-pair group 0..7 -> d = 2dg, 2dg+1
    const int wsl  = w & 1;                  // i-half
    const int mp   = tid & 255;
    const int n0   = tid >> 8;               // 0..3, wave-uniform

    // z-phase A slice: 2 d-rows x 8 i per lane, stride-2 v2f (2-way LDS aliasing = free)
    const int ibase = wsl * 512 + 2 * lane;
    v2f a0p[4], a1p[4];
    #pragma unroll
    for (int k = 0; k < 4; ++k) {
        a0p[k] = *(const v2f*)&A_T_hh[(2 * dg) * 1024 + ibase + 128 * k];
        a1p[k] = *(const v2f*)&A_T_hh[(2 * dg + 1) * 1024 + ibase + 128 * k];
    }

    // folded hh table, register-resident: wh[g][d] = Whh2[u=(n0+4g)*256+mp][d]
    float wh[4][16];
    #pragma unroll
    for (int g = 0; g < 4; ++g) {
        const float4* src = (const float4*)&Whh2[(size_t)((n0 + 4 * g) * 256 + mp) * 16];
        float4 f0 = src[0], f1 = src[1], f2 = src[2], f3 = src[3];
        wh[g][0] = f0.x;  wh[g][1] = f0.y;  wh[g][2]  = f0.z;  wh[g][3]  = f0.w;
        wh[g][4] = f1.x;  wh[g][5] = f1.y;  wh[g][6]  = f1.z;  wh[g][7]  = f1.w;
        wh[g][8] = f2.x;  wh[g][9] = f2.y;  wh[g][10] = f2.z;  wh[g][11] = f2.w;
        wh[g][12] = f3.x; wh[g][13] = f3.y; wh[g][14] = f3.z;  wh[g][15] = f3.w;
    }

    // D2 weights (ih): m2i[e] = M2ih[e][mp]
    float m2i[16];
    #pragma unroll
    for (int e = 0; e < 16; ++e) m2i[e] = M2ih[e * 256 + mp];

    float bias0 = b_ih[tid]        + b_hh[tid];
    float bias1 = b_ih[1024 + tid] + b_hh[1024 + tid];
    float bias2 = b_ih[2048 + tid] + b_hh[2048 + tid];
    float bias3 = b_ih[3072 + tid] + b_hh[3072 + tid];

    Lh[tid] = 0.f;
    float h = 0.f, c = 0.f;
    float yp0 = 0.f, yp1 = 0.f, yp2 = 0.f, yp3 = 0.f;  // rotating prefetch retire
    __syncthreads();

    const float* yrow = y_ih_g + (size_t)b * (NT * 256);
    float*       orow = out + (size_t)b * (NT * 1024);
    float pfacc = 0.f;
    const int e16 = lane & 15;

    for (int t = 0; t < NT; ++t) {
        // (0) scalar y loads for THIS step (wave-uniform -> s_load, lands in
        //     phase A) + L2-warming vector load 4 steps ahead (vmcnt-only,
        //     retired 4-deep rotated — never stalls this step).
        const int ybase = __builtin_amdgcn_readfirstlane(t * 256 + n0 * 16);
        float yv[4][16];
        #pragma unroll
        for (int g = 0; g < 4; ++g)
            #pragma unroll
            for (int e = 0; e < 16; ++e)
                yv[g][e] = yrow[ybase + g * 64 + e];
        float ypn = 0.f;
        {
            int tpf = (t + 4 < NT) ? (t + 4) : (NT - 1);
            if (tid < 256) ypn = yrow[tpf * 256 + tid];
        }

        // --- (A) z partials: wave (dg,wsl) covers d={2dg,2dg+1}, i in [wsl*512,+512)
        float p0, p1;
        {
            const v2f* hv2 = (const v2f*)&Lh[ibase];
            v2f hp0 = hv2[0], hp1 = hv2[64], hp2 = hv2[128], hp3 = hv2[192];
            v2f s0 = hp0 * a0p[0]; s0 += hp1 * a0p[1]; s0 += hp2 * a0p[2]; s0 += hp3 * a0p[3];
            v2f s1 = hp0 * a1p[0]; s1 += hp1 * a1p[1]; s1 += hp2 * a1p[2]; s1 += hp3 * a1p[3];
            p0 = s0.x + s0.y;
            p1 = s1.x + s1.y;
        }
        p0 = wave_red_sum(p0);              // DPP, VALU pipe
        p1 = wave_red_sum(p1);
        if (lane == 63) *(v2f*)&Lz[wsl][2 * dg] = mkv2(p0, p1);  // plain write

        // --- (D2, hoisted) bias + ih contribution — independent of z, fills the
        //     DPP latency window and shortens the post-barrier chain.
        float acc0 = bias0, acc1 = bias1, acc2 = bias2, acc3 = bias3;
        #pragma unroll
        for (int e = 0; e < 16; ++e) {
            acc0 = fmaf(yv[0][e], m2i[e], acc0);
            acc1 = fmaf(yv[1][e], m2i[e], acc1);
            acc2 = fmaf(yv[2][e], m2i[e], acc2);
            acc3 = fmaf(yv[3][e], m2i[e], acc3);
        }
        bar_lgkm();   // bar#1: z partials visible

        // --- (Z) z -> SGPRs: 8 bytes/lane LDS + 16 readlane (no broadcast b128s)
        float sz[16];
        {
            float zlo = Lz[0][e16];
            float zhi = Lz[1][e16];
            float zsum = zlo + zhi;               // lane l holds z[l&15]
            int zi = __builtin_bit_cast(int, zsum);
            #pragma unroll
            for (int e = 0; e < 16; ++e)
                sz[e] = __builtin_bit_cast(float, __builtin_amdgcn_readlane(zi, e));
        }

        // --- (D1) hh contribution: pure VALU, SGPR-z x register-wh
        #pragma unroll
        for (int d = 0; d < 16; ++d) {
            acc0 = fmaf(sz[d], wh[0][d], acc0);
            acc1 = fmaf(sz[d], wh[1][d], acc1);
            acc2 = fmaf(sz[d], wh[2][d], acc2);
            acc3 = fmaf(sz[d], wh[3][d], acc3);
        }

        // --- (E) LSTM cell
        float ig = sigm(acc0);
        float fg = sigm(acc1);
        float gg = tanh_fast(acc2);
        float og = sigm(acc3);
        c = fg * c + ig * gg;
        h = og * tanh_fast(c);

        Lh[tid] = h;
        orow[t * 1024 + tid] = h;           // fire-and-forget (vmcnt, not drained by bar)
        // retire the prefetch issued 4 steps ago: vmcnt wait auto-satisfied.
        pfacc += yp0; yp0 = yp1; yp1 = yp2; yp2 = yp3; yp3 = ypn;
        bar_lgkm();   // bar#2: Lh(t) + Lz reads drained; next step may overwrite
    }

    out[HID_OFF + b * 1024 + tid] = h;
    out[HID_OFF + HC_SZ + b * 1024 + tid] = c;
    float pfsink = pfacc + yp0 + yp1 + yp2 + yp3;
    if (tid < 256) pfdump[tid] = pfsink;     // sink (ws, never read)
}

extern "C" void kernel_launch(void* const* d_in, const int* in_sizes, int n_in,
                              void* d_out, int out_size, void* d_ws, size_t ws_size,
                              hipStream_t stream) {
    const float* x     = (const float*)d_in[0];
    const float* ihg1  = (const float*)d_in[1];
    const float* ihg2  = (const float*)d_in[2];
    const float* ihg3  = (const float*)d_in[3];
    const float* ihg4  = (const float*)d_in[4];
    const float* ihg5  = (const float*)d_in[5];
    const float* ihg6  = (const float*)d_in[6];
    const float* hhg1  = (const float*)d_in[7];
    const float* hhg2  = (const float*)d_in[8];
    const float* hhg3  = (const float*)d_in[9];
    const float* hhg4  = (const float*)d_in[10];
    const float* hhg5  = (const float*)d_in[11];
    const float* hhg6  = (const float*)d_in[12];
    const float* b_ih  = (const float*)d_in[13];
    const float* b_hh  = (const float*)d_in[14];
    float* out = (float*)d_out;

    float* ws     = (float*)d_ws;
    float* ATih   = ws;
    float* AThh   = ws + 16384;
    float* M2ih   = ws + 32768;
    float* M2hh   = ws + 36864;
    float* Whh2   = ws + 40960;
    float* pfdump = ws + 106496;
    float* yih    = ws + 107520;

    hipLaunchKernelGGL(k0_build, dim3(2, 4), dim3(256), 0, stream,
                       ihg1, ihg2, ihg3, ihg5, ihg6,
                       hhg1, hhg2, hhg3, hhg5, hhg6,
                       ATih, M2ih, AThh, M2hh);
    hipLaunchKernelGGL(k0b_whh, dim3(16), dim3(256), 0, stream,
                       hhg4, M2hh, Whh2);
    hipLaunchKernelGGL(k1_zy, dim3(1024), dim3(256), 0, stream,
                       x, ATih, ihg4, yih);
    hipLaunchKernelGGL(k2_lstm, dim3(NB), dim3(1024), 0, stream,
                       AThh, Whh2, M2ih, yih, b_ih, b_hh, pfdump, out);
}